// Round 4
// baseline (299.790 us; speedup 1.0000x reference)
//
#include <hip/hip_runtime.h>
#include <stdint.h>

// Problem constants: B=2, S=2048, HIDDEN=1024, NH=16, D=64
// M = B*S = 4096, N1 = 3072, K = 1024, N2 = 1024, BH = 32

#define DEV static __device__ __forceinline__

typedef unsigned short u16;
typedef __attribute__((ext_vector_type(4))) float f32x4;
typedef __attribute__((ext_vector_type(16))) float f32x16;
typedef __bf16 bf16x8 __attribute__((ext_vector_type(8)));
typedef __attribute__((ext_vector_type(8))) unsigned short u16x8;
typedef __attribute__((ext_vector_type(4))) unsigned short u16x4;

// 0.125 * log2(e): folded into Q so softmax weights are exp2(acc)
#define QSCALE 0.18033688011112042f

DEV u16 f2bf(float f) {
    unsigned u = __builtin_bit_cast(unsigned, f);
    u += 0x7fffu + ((u >> 16) & 1u);
    return (u16)(u >> 16);
}
DEV float bf2f(u16 h) {
    unsigned u = ((unsigned)h) << 16;
    return __builtin_bit_cast(float, u);
}

// async global->LDS, 16B per lane. LDS dest must be wave-uniform base + lane*16.
DEV void async_copy16(const void* g, void* l) {
    __builtin_amdgcn_global_load_lds(
        (__attribute__((address_space(1))) void*)(g),
        (__attribute__((address_space(3))) void*)(l), 16, 0, 0);
}

// ---------------- elementwise cast kernels ----------------

__global__ __launch_bounds__(256) void cast_f32_bf16(
    const float* __restrict__ src, u16* __restrict__ dst, int n4) {
    int i = blockIdx.x * 256 + threadIdx.x;
    if (i >= n4) return;
    f32x4 v = *(const f32x4*)(src + (size_t)i * 4);
    u16x4 o;
#pragma unroll
    for (int j = 0; j < 4; j++) o[j] = f2bf(v[j]);
    *(u16x4*)(dst + (size_t)i * 4) = o;
}

// src [rows][cols] fp32  ->  dst [cols][rows] bf16
__global__ __launch_bounds__(256) void transpose_cast(
    const float* __restrict__ src, u16* __restrict__ dst, int rows, int cols) {
    __shared__ float tile[32][33];
    int c0 = blockIdx.x * 32, r0 = blockIdx.y * 32;
    int tx = threadIdx.x, ty = threadIdx.y;  // block (32,8)
#pragma unroll
    for (int i = 0; i < 4; i++)
        tile[ty + i * 8][tx] = src[(size_t)(r0 + ty + i * 8) * cols + c0 + tx];
    __syncthreads();
#pragma unroll
    for (int i = 0; i < 4; i++)
        dst[(size_t)(c0 + ty + i * 8) * rows + r0 + tx] = f2bf(tile[tx][ty + i * 8]);
}

// ---------------- 128x128 bf16 MFMA GEMM core ----------------
DEV void gemm128_core(const u16* __restrict__ A, const u16* __restrict__ Bt,
                      int m0, int n0, int Kdim, u16* As, u16* Bs,
                      f32x4 (*acc)[4]) {
    const int t = threadIdx.x;
    const int wave = t >> 6;
    const int lane = t & 63;
    const int quad = lane >> 4;
    const int l16 = lane & 15;
    const int wr = wave >> 1;
    const int wc = wave & 1;

    for (int kt = 0; kt < Kdim; kt += 32) {
#pragma unroll
        for (int i = 0; i < 2; i++) {
            int idx = i * 256 + t;
            int row = idx >> 2, kc = idx & 3;
            async_copy16(A + (size_t)(m0 + row) * Kdim + kt + kc * 8, &As[idx * 8]);
            async_copy16(Bt + (size_t)(n0 + row) * Kdim + kt + kc * 8, &Bs[idx * 8]);
        }
        __syncthreads();
        bf16x8 af[4], bfr[4];
#pragma unroll
        for (int mt = 0; mt < 4; mt++)
            af[mt] = *(const bf16x8*)&As[(wr * 64 + mt * 16 + l16) * 32 + quad * 8];
#pragma unroll
        for (int nt = 0; nt < 4; nt++)
            bfr[nt] = *(const bf16x8*)&Bs[(wc * 64 + nt * 16 + l16) * 32 + quad * 8];
#pragma unroll
        for (int mt = 0; mt < 4; mt++)
#pragma unroll
            for (int nt = 0; nt < 4; nt++)
                acc[mt][nt] = __builtin_amdgcn_mfma_f32_16x16x32_bf16(
                    af[mt], bfr[nt], acc[mt][nt], 0, 0, 0);
        __syncthreads();
    }
}

// GEMM1: qkv projection, epilogue scatters into q/k/v [bh][s][d] bf16.
__global__ __launch_bounds__(256) void gemm_qkv(
    const u16* __restrict__ A, const u16* __restrict__ Bt,
    u16* __restrict__ qb, u16* __restrict__ kb, u16* __restrict__ vb) {
    __shared__ __align__(16) u16 As[128 * 32];
    __shared__ __align__(16) u16 Bs[128 * 32];
    const int m0 = blockIdx.y * 128;
    const int n0 = blockIdx.x * 128;
    f32x4 acc[4][4];
#pragma unroll
    for (int i = 0; i < 4; i++)
#pragma unroll
        for (int j = 0; j < 4; j++) acc[i][j] = {0.f, 0.f, 0.f, 0.f};

    gemm128_core(A, Bt, m0, n0, 1024, As, Bs, acc);

    const int t = threadIdx.x;
    const int wave = t >> 6, lane = t & 63;
    const int quad = lane >> 4, l16 = lane & 15;
    const int wr = wave >> 1, wc = wave & 1;
#pragma unroll
    for (int nt = 0; nt < 4; nt++) {
        int nn = n0 + wc * 64 + nt * 16 + l16;
        int tsel = nn >> 10;           // 0=q 1=k 2=v
        int rem = nn & 1023;
        int h = rem >> 6, d = rem & 63;
        u16* dst = tsel == 0 ? qb : (tsel == 1 ? kb : vb);
        float scl = tsel == 0 ? QSCALE : 1.0f;
#pragma unroll
        for (int mt = 0; mt < 4; mt++) {
#pragma unroll
            for (int r = 0; r < 4; r++) {
                int mm = m0 + wr * 64 + mt * 16 + quad * 4 + r;
                int b = mm >> 11, s = mm & 2047;
                dst[(size_t)((b * 16 + h) * 2048 + s) * 64 + d] = f2bf(acc[mt][nt][r] * scl);
            }
        }
    }
}

// GEMM2: out = values @ w_o, fp32 output
__global__ __launch_bounds__(256) void gemm_out(
    const u16* __restrict__ A, const u16* __restrict__ Bt,
    float* __restrict__ out) {
    __shared__ __align__(16) u16 As[128 * 32];
    __shared__ __align__(16) u16 Bs[128 * 32];
    const int m0 = blockIdx.y * 128;
    const int n0 = blockIdx.x * 128;
    f32x4 acc[4][4];
#pragma unroll
    for (int i = 0; i < 4; i++)
#pragma unroll
        for (int j = 0; j < 4; j++) acc[i][j] = {0.f, 0.f, 0.f, 0.f};

    gemm128_core(A, Bt, m0, n0, 1024, As, Bs, acc);

    const int t = threadIdx.x;
    const int wave = t >> 6, lane = t & 63;
    const int quad = lane >> 4, l16 = lane & 15;
    const int wr = wave >> 1, wc = wave & 1;
#pragma unroll
    for (int nt = 0; nt < 4; nt++) {
        int nn = n0 + wc * 64 + nt * 16 + l16;
#pragma unroll
        for (int mt = 0; mt < 4; mt++) {
#pragma unroll
            for (int r = 0; r < 4; r++) {
                int mm = m0 + wr * 64 + mt * 16 + quad * 4 + r;
                out[(size_t)mm * 1024 + nn] = acc[mt][nt][r];
            }
        }
    }
}

// ---------------- attention passes (32x32 MFMA, reg-pipelined) ----------------
// No max subtraction: scores are O(+-5); exp(s)/sum(exp(s)) == softmax.
// Q pre-scaled by 0.125*log2e so weights are exp2(acc).
// 32x32x16 layouts: A/B [row=lane&31][k=(lane>>5)*8+j];
// C/D col=lane&31, row=(r&3)+8*(r>>2)+4*(lane>>5).
//
// Pass 1: wave = 32 q-rows, sweeps 512 k-cols in 16 tiles of 32.
// Partial row-sums -> lp[kchunk][bh*2048+q].
__global__ __launch_bounds__(256) void attn_pass1(
    const u16* __restrict__ qb, const u16* __restrict__ kb,
    float* __restrict__ lp) {
    const int kchunk = blockIdx.x & 3;
    const int qblk = (blockIdx.x >> 2) & 15;
    const int bh = blockIdx.x >> 6;
    const int wave = threadIdx.x >> 6;
    const int lane = threadIdx.x & 63;
    const int l32 = lane & 31, half = lane >> 5;
    const int q0 = qblk * 128 + wave * 32;

    const u16* Qr = qb + (size_t)(bh * 2048 + q0 + l32) * 64 + half * 8;
    bf16x8 a[4];
#pragma unroll
    for (int f = 0; f < 4; f++) a[f] = *(const bf16x8*)&Qr[f * 16];

    const u16* Kc = kb + (size_t)(bh * 2048 + kchunk * 512 + l32) * 64 + half * 8;
    float lsum[16];
#pragma unroll
    for (int r = 0; r < 16; r++) lsum[r] = 0.f;

    bf16x8 nb[4];
#pragma unroll
    for (int f = 0; f < 4; f++) nb[f] = *(const bf16x8*)&Kc[f * 16];

    for (int nt = 0; nt < 16; nt++) {
        bf16x8 cb[4];
#pragma unroll
        for (int f = 0; f < 4; f++) cb[f] = nb[f];
        if (nt < 15) {
            const u16* Kn = Kc + (size_t)(nt + 1) * 32 * 64;
#pragma unroll
            for (int f = 0; f < 4; f++) nb[f] = *(const bf16x8*)&Kn[f * 16];
        }
        f32x16 acc;
#pragma unroll
        for (int r = 0; r < 16; r++) acc[r] = 0.f;
#pragma unroll
        for (int f = 0; f < 4; f++)
            acc = __builtin_amdgcn_mfma_f32_32x32x16_bf16(a[f], cb[f], acc, 0, 0, 0);
#pragma unroll
        for (int r = 0; r < 16; r++)
            lsum[r] += __builtin_amdgcn_exp2f(acc[r]);
    }
    // reduce each row across the 32 columns (lanes within each half-wave)
#pragma unroll
    for (int r = 0; r < 16; r++) {
        float v = lsum[r];
        v += __shfl_xor(v, 1);
        v += __shfl_xor(v, 2);
        v += __shfl_xor(v, 4);
        v += __shfl_xor(v, 8);
        v += __shfl_xor(v, 16);
        lsum[r] = v;
    }
    if (l32 == 0) {
        float* dst = lp + kchunk * 65536 + bh * 2048 + q0 + half * 4;
#pragma unroll
        for (int r = 0; r < 16; r++)
            dst[(r & 3) + 8 * (r >> 2)] = lsum[r];
    }
}

// li = 1 / (sum of 4 partials)
__global__ __launch_bounds__(256) void reduce_li(
    const float* __restrict__ lp, float* __restrict__ li) {
    int i = blockIdx.x * 256 + threadIdx.x;  // 65536
    li[i] = 1.0f / (lp[i] + lp[65536 + i] + lp[131072 + i] + lp[196608 + i]);
}

// Pass 2: wave = 32 k-cols, sweeps 512 q-rows in 16 tiles of 32.
// colsum partial -> cp[qchunk][bh*2048+k].
__global__ __launch_bounds__(256) void attn_pass2(
    const u16* __restrict__ qb, const u16* __restrict__ kb,
    const float* __restrict__ li_ws, float* __restrict__ cp) {
    const int qchunk = blockIdx.x & 3;
    const int kblk = (blockIdx.x >> 2) & 15;
    const int bh = blockIdx.x >> 6;
    const int wave = threadIdx.x >> 6;
    const int lane = threadIdx.x & 63;
    const int l32 = lane & 31, half = lane >> 5;
    const int k0 = kblk * 128 + wave * 32;

    const u16* Kr = kb + (size_t)(bh * 2048 + k0 + l32) * 64 + half * 8;
    bf16x8 b[4];
#pragma unroll
    for (int f = 0; f < 4; f++) b[f] = *(const bf16x8*)&Kr[f * 16];

    const u16* Qc = qb + (size_t)(bh * 2048 + qchunk * 512 + l32) * 64 + half * 8;
    const float* li_b = li_ws + bh * 2048 + qchunk * 512 + half * 4;

    float cs[4] = {0.f, 0.f, 0.f, 0.f};

    bf16x8 na[4];
    f32x4 nli[4];
#pragma unroll
    for (int f = 0; f < 4; f++) na[f] = *(const bf16x8*)&Qc[f * 16];
#pragma unroll
    for (int r2 = 0; r2 < 4; r2++) nli[r2] = *(const f32x4*)&li_b[r2 * 8];

    for (int qt = 0; qt < 16; qt++) {
        bf16x8 ca[4];
        f32x4 cli[4];
#pragma unroll
        for (int f = 0; f < 4; f++) ca[f] = na[f];
#pragma unroll
        for (int r2 = 0; r2 < 4; r2++) cli[r2] = nli[r2];
        if (qt < 15) {
            const u16* Qn = Qc + (size_t)(qt + 1) * 32 * 64;
            const float* ln = li_b + (qt + 1) * 32;
#pragma unroll
            for (int f = 0; f < 4; f++) na[f] = *(const bf16x8*)&Qn[f * 16];
#pragma unroll
            for (int r2 = 0; r2 < 4; r2++) nli[r2] = *(const f32x4*)&ln[r2 * 8];
        }
        f32x16 acc;
#pragma unroll
        for (int r = 0; r < 16; r++) acc[r] = 0.f;
#pragma unroll
        for (int f = 0; f < 4; f++)
            acc = __builtin_amdgcn_mfma_f32_32x32x16_bf16(ca[f], b[f], acc, 0, 0, 0);
#pragma unroll
        for (int r = 0; r < 16; r++)
            cs[r >> 2] += __builtin_amdgcn_exp2f(acc[r]) * cli[r >> 2][r & 3];
    }
    float v = cs[0] + cs[1] + cs[2] + cs[3];
    v += __shfl_xor(v, 32);
    if (lane < 32)
        cp[qchunk * 65536 + bh * 2048 + k0 + lane] = v;
}

// values[b][s][h*64+d] = colsum[bh][s] * v[bh][s][d]  (bf16); sums 4 partials
__global__ __launch_bounds__(256) void scale_v(
    const u16* __restrict__ vb, const float* __restrict__ cp,
    u16* __restrict__ valsb) {
    int tid = blockIdx.x * 256 + threadIdx.x;  // 524288 threads, 8 elems each
    int base = tid << 3;
    int bh = base >> 17;           // / (2048*64)
    int rem = base & 131071;
    int s = rem >> 6;
    int d0 = rem & 63;
    int ci = bh * 2048 + s;
    float cs = cp[ci] + cp[65536 + ci] + cp[131072 + ci] + cp[196608 + ci];
    u16x8 v = *(const u16x8*)(vb + (size_t)base);
    u16x8 o;
#pragma unroll
    for (int i = 0; i < 8; i++) o[i] = f2bf(bf2f(v[i]) * cs);
    int b = bh >> 4, h = bh & 15;
    *(u16x8*)(valsb + (size_t)((b * 2048 + s) * 1024) + h * 64 + d0) = o;
}

// ---------------- launch ----------------

extern "C" void kernel_launch(void* const* d_in, const int* in_sizes, int n_in,
                              void* d_out, int out_size, void* d_ws, size_t ws_size,
                              hipStream_t stream) {
    const float* x    = (const float*)d_in[0];   // [2,2048,1024]
    const float* wqkv = (const float*)d_in[1];   // [1024,3072]
    const float* wo   = (const float*)d_in[2];   // [1024,1024]
    float* out = (float*)d_out;                  // [2,2048,1024] fp32
    char* ws = (char*)d_ws;

    u16* xb      = (u16*)(ws);                   // [4096][1024] bf16 (dead after gemm_qkv)
    u16* wqkvT   = (u16*)(ws + 8388608);         // [3072][1024] bf16
    u16* woT     = (u16*)(ws + 14680064);        // [1024][1024] bf16
    u16* qb      = (u16*)(ws + 16777216);        // [32][2048][64] bf16
    u16* kb      = (u16*)(ws + 25165824);
    u16* vb      = (u16*)(ws + 33554432);
    float* li_ws = (float*)(ws + 41943040);      // [32][2048]
    u16* valsb   = (u16*)(ws + 42467328);        // [4096][1024] bf16
    // partial buffers alias xb (dead after gemm_qkv): 2 x 1MB
    float* lp    = (float*)(ws);                 // [4][32][2048]
    float* cp    = (float*)(ws + 1048576);       // [4][32][2048]

    cast_f32_bf16<<<4096, 256, 0, stream>>>(x, xb, 1048576);
    transpose_cast<<<dim3(96, 32), dim3(32, 8), 0, stream>>>(wqkv, wqkvT, 1024, 3072);
    transpose_cast<<<dim3(32, 32), dim3(32, 8), 0, stream>>>(wo, woT, 1024, 1024);
    gemm_qkv<<<dim3(24, 32), 256, 0, stream>>>(xb, wqkvT, qb, kb, vb);
    attn_pass1<<<2048, 256, 0, stream>>>(qb, kb, lp);
    reduce_li<<<256, 256, 0, stream>>>(lp, li_ws);
    attn_pass2<<<2048, 256, 0, stream>>>(qb, kb, li_ws, cp);
    scale_v<<<2048, 256, 0, stream>>>(vb, cp, valsb);
    gemm_out<<<dim3(8, 32), 256, 0, stream>>>(valsb, woT, out);
}

// Round 5
// 209.251 us; speedup vs baseline: 1.4327x; 1.4327x over previous
//
#include <hip/hip_runtime.h>
#include <stdint.h>

// Problem constants: B=2, S=2048, HIDDEN=1024, NH=16, D=64
// M = B*S = 4096, N1 = 3072, K = 1024, N2 = 1024, BH = 32

#define DEV static __device__ __forceinline__

typedef unsigned short u16;
typedef __attribute__((ext_vector_type(4))) float f32x4;
typedef __attribute__((ext_vector_type(16))) float f32x16;
typedef __bf16 bf16x8 __attribute__((ext_vector_type(8)));
typedef __attribute__((ext_vector_type(8))) unsigned short u16x8;
typedef __attribute__((ext_vector_type(4))) unsigned short u16x4;

// 0.125 * log2(e): folded into Q so softmax weights are exp2(acc)
#define QSCALE 0.18033688011112042f

DEV u16 f2bf(float f) {
    unsigned u = __builtin_bit_cast(unsigned, f);
    u += 0x7fffu + ((u >> 16) & 1u);
    return (u16)(u >> 16);
}
DEV float bf2f(u16 h) {
    unsigned u = ((unsigned)h) << 16;
    return __builtin_bit_cast(float, u);
}

// async global->LDS, 16B per lane. LDS dest must be wave-uniform base + lane*16.
DEV void async_copy16(const void* g, void* l) {
    __builtin_amdgcn_global_load_lds(
        (__attribute__((address_space(1))) void*)(g),
        (__attribute__((address_space(3))) void*)(l), 16, 0, 0);
}

// ---------------- elementwise cast kernels ----------------

__global__ __launch_bounds__(256) void cast_f32_bf16(
    const float* __restrict__ src, u16* __restrict__ dst, int n4) {
    int i = blockIdx.x * 256 + threadIdx.x;
    if (i >= n4) return;
    f32x4 v = *(const f32x4*)(src + (size_t)i * 4);
    u16x4 o;
#pragma unroll
    for (int j = 0; j < 4; j++) o[j] = f2bf(v[j]);
    *(u16x4*)(dst + (size_t)i * 4) = o;
}

// src [rows][cols] fp32  ->  dst [cols][rows] bf16
__global__ __launch_bounds__(256) void transpose_cast(
    const float* __restrict__ src, u16* __restrict__ dst, int rows, int cols) {
    __shared__ float tile[32][33];
    int c0 = blockIdx.x * 32, r0 = blockIdx.y * 32;
    int tx = threadIdx.x, ty = threadIdx.y;  // block (32,8)
#pragma unroll
    for (int i = 0; i < 4; i++)
        tile[ty + i * 8][tx] = src[(size_t)(r0 + ty + i * 8) * cols + c0 + tx];
    __syncthreads();
#pragma unroll
    for (int i = 0; i < 4; i++)
        dst[(size_t)(c0 + ty + i * 8) * rows + r0 + tx] = f2bf(tile[tx][ty + i * 8]);
}

// ---------------- 128x128 bf16 MFMA GEMM core ----------------
DEV void gemm128_core(const u16* __restrict__ A, const u16* __restrict__ Bt,
                      int m0, int n0, int Kdim, u16* As, u16* Bs,
                      f32x4 (*acc)[4]) {
    const int t = threadIdx.x;
    const int wave = t >> 6;
    const int lane = t & 63;
    const int quad = lane >> 4;
    const int l16 = lane & 15;
    const int wr = wave >> 1;
    const int wc = wave & 1;

    for (int kt = 0; kt < Kdim; kt += 32) {
#pragma unroll
        for (int i = 0; i < 2; i++) {
            int idx = i * 256 + t;
            int row = idx >> 2, kc = idx & 3;
            async_copy16(A + (size_t)(m0 + row) * Kdim + kt + kc * 8, &As[idx * 8]);
            async_copy16(Bt + (size_t)(n0 + row) * Kdim + kt + kc * 8, &Bs[idx * 8]);
        }
        __syncthreads();
        bf16x8 af[4], bfr[4];
#pragma unroll
        for (int mt = 0; mt < 4; mt++)
            af[mt] = *(const bf16x8*)&As[(wr * 64 + mt * 16 + l16) * 32 + quad * 8];
#pragma unroll
        for (int nt = 0; nt < 4; nt++)
            bfr[nt] = *(const bf16x8*)&Bs[(wc * 64 + nt * 16 + l16) * 32 + quad * 8];
#pragma unroll
        for (int mt = 0; mt < 4; mt++)
#pragma unroll
            for (int nt = 0; nt < 4; nt++)
                acc[mt][nt] = __builtin_amdgcn_mfma_f32_16x16x32_bf16(
                    af[mt], bfr[nt], acc[mt][nt], 0, 0, 0);
        __syncthreads();
    }
}

// GEMM1: qkv projection, epilogue scatters into q/k/v [bh][s][d] bf16.
__global__ __launch_bounds__(256) void gemm_qkv(
    const u16* __restrict__ A, const u16* __restrict__ Bt,
    u16* __restrict__ qb, u16* __restrict__ kb, u16* __restrict__ vb) {
    __shared__ __align__(16) u16 As[128 * 32];
    __shared__ __align__(16) u16 Bs[128 * 32];
    const int m0 = blockIdx.y * 128;
    const int n0 = blockIdx.x * 128;
    f32x4 acc[4][4];
#pragma unroll
    for (int i = 0; i < 4; i++)
#pragma unroll
        for (int j = 0; j < 4; j++) acc[i][j] = {0.f, 0.f, 0.f, 0.f};

    gemm128_core(A, Bt, m0, n0, 1024, As, Bs, acc);

    const int t = threadIdx.x;
    const int wave = t >> 6, lane = t & 63;
    const int quad = lane >> 4, l16 = lane & 15;
    const int wr = wave >> 1, wc = wave & 1;
#pragma unroll
    for (int nt = 0; nt < 4; nt++) {
        int nn = n0 + wc * 64 + nt * 16 + l16;
        int tsel = nn >> 10;           // 0=q 1=k 2=v
        int rem = nn & 1023;
        int h = rem >> 6, d = rem & 63;
        u16* dst = tsel == 0 ? qb : (tsel == 1 ? kb : vb);
        float scl = tsel == 0 ? QSCALE : 1.0f;
#pragma unroll
        for (int mt = 0; mt < 4; mt++) {
#pragma unroll
            for (int r = 0; r < 4; r++) {
                int mm = m0 + wr * 64 + mt * 16 + quad * 4 + r;
                int b = mm >> 11, s = mm & 2047;
                dst[(size_t)((b * 16 + h) * 2048 + s) * 64 + d] = f2bf(acc[mt][nt][r] * scl);
            }
        }
    }
}

// GEMM2: out = values @ w_o, fp32 output
__global__ __launch_bounds__(256) void gemm_out(
    const u16* __restrict__ A, const u16* __restrict__ Bt,
    float* __restrict__ out) {
    __shared__ __align__(16) u16 As[128 * 32];
    __shared__ __align__(16) u16 Bs[128 * 32];
    const int m0 = blockIdx.y * 128;
    const int n0 = blockIdx.x * 128;
    f32x4 acc[4][4];
#pragma unroll
    for (int i = 0; i < 4; i++)
#pragma unroll
        for (int j = 0; j < 4; j++) acc[i][j] = {0.f, 0.f, 0.f, 0.f};

    gemm128_core(A, Bt, m0, n0, 1024, As, Bs, acc);

    const int t = threadIdx.x;
    const int wave = t >> 6, lane = t & 63;
    const int quad = lane >> 4, l16 = lane & 15;
    const int wr = wave >> 1, wc = wave & 1;
#pragma unroll
    for (int nt = 0; nt < 4; nt++) {
        int nn = n0 + wc * 64 + nt * 16 + l16;
#pragma unroll
        for (int mt = 0; mt < 4; mt++) {
#pragma unroll
            for (int r = 0; r < 4; r++) {
                int mm = m0 + wr * 64 + mt * 16 + quad * 4 + r;
                out[(size_t)mm * 1024 + nn] = acc[mt][nt][r];
            }
        }
    }
}

// ---------------- attention passes (LDS-staged, GEMM-style) ----------------
// No max subtraction: scores are O(+-5); exp(s)/sum(exp(s)) == softmax.
// Q pre-scaled by 0.125*log2e so weights are exp2(acc).
// 32x32x16 layouts: A/B [row=lane&31][k=(lane>>5)*8+j over f*16];
// C/D col=lane&31, row=(r&3)+8*(r>>2)+4*(lane>>5).
//
// Pass 1: block = 4 waves x 32 q-rows = 128 q-rows; K staged in LDS as two
// [64][32]-u16 sub-tiles (64B row stride, the measured conflict-free layout),
// shared by all 4 waves. Sweep 1024 k per block (2 chunks).
__global__ __launch_bounds__(256) void attn_pass1(
    const u16* __restrict__ qb, const u16* __restrict__ kb,
    float* __restrict__ lp) {
    __shared__ __align__(16) u16 Ks0[64 * 32];  // d 0..31
    __shared__ __align__(16) u16 Ks1[64 * 32];  // d 32..63
    const int t = threadIdx.x;
    const int wave = t >> 6;
    const int lane = t & 63;
    const int l32 = lane & 31, half = lane >> 5;
    const int kchunk = blockIdx.x & 1;
    const int qblk = (blockIdx.x >> 1) & 15;
    const int bh = blockIdx.x >> 5;
    const int q0 = qblk * 128 + wave * 32;

    // persistent Q fragments: A[m=l32][k=f*16+half*8+j]
    const u16* Qr = qb + (size_t)(bh * 2048 + q0 + l32) * 64 + half * 8;
    bf16x8 a[4];
#pragma unroll
    for (int f = 0; f < 4; f++) a[f] = *(const bf16x8*)&Qr[f * 16];

    const u16* Kbase = kb + (size_t)(bh * 2048 + kchunk * 1024) * 64;
    const int srow = t >> 2, sc = (t & 3) * 8;

    float lsum[16];
#pragma unroll
    for (int r = 0; r < 16; r++) lsum[r] = 0.f;

    for (int kt = 0; kt < 16; kt++) {
        const u16* src = Kbase + (size_t)(kt * 64 + srow) * 64 + sc;
        async_copy16(src, &Ks0[t * 8]);
        async_copy16(src + 32, &Ks1[t * 8]);
        __syncthreads();
#pragma unroll
        for (int sub = 0; sub < 2; sub++) {
            const int row = sub * 32 + l32;
            bf16x8 bfr[4];
            bfr[0] = *(const bf16x8*)&Ks0[row * 32 + half * 8];
            bfr[1] = *(const bf16x8*)&Ks0[row * 32 + 16 + half * 8];
            bfr[2] = *(const bf16x8*)&Ks1[row * 32 + half * 8];
            bfr[3] = *(const bf16x8*)&Ks1[row * 32 + 16 + half * 8];
            f32x16 acc;
#pragma unroll
            for (int r = 0; r < 16; r++) acc[r] = 0.f;
#pragma unroll
            for (int f = 0; f < 4; f++)
                acc = __builtin_amdgcn_mfma_f32_32x32x16_bf16(a[f], bfr[f], acc, 0, 0, 0);
#pragma unroll
            for (int r = 0; r < 16; r++)
                lsum[r] += __builtin_amdgcn_exp2f(acc[r]);
        }
        __syncthreads();
    }
    // reduce each row across the 32 k-columns (lanes within each half)
#pragma unroll
    for (int r = 0; r < 16; r++) {
        float v = lsum[r];
        v += __shfl_xor(v, 1);
        v += __shfl_xor(v, 2);
        v += __shfl_xor(v, 4);
        v += __shfl_xor(v, 8);
        v += __shfl_xor(v, 16);
        lsum[r] = v;
    }
    if (l32 == 0) {
        float* dst = lp + kchunk * 65536 + bh * 2048 + q0 + half * 4;
#pragma unroll
        for (int r = 0; r < 16; r++)
            dst[(r & 3) + 8 * (r >> 2)] = lsum[r];
    }
}

// li = 1 / (sum of 2 partials)
__global__ __launch_bounds__(256) void reduce_li(
    const float* __restrict__ lp, float* __restrict__ li) {
    int i = blockIdx.x * 256 + threadIdx.x;  // 65536
    li[i] = 1.0f / (lp[i] + lp[65536 + i]);
}

// Pass 2: block = 4 waves x 32 k-cols = 128 k-cols; Q staged in LDS (same
// layout), li read direct (L1-resident, reused by all waves). colsum partial
// per lane (col = l32), accumulated in-register across all staged q-rows.
__global__ __launch_bounds__(256) void attn_pass2(
    const u16* __restrict__ qb, const u16* __restrict__ kb,
    const float* __restrict__ li_ws, float* __restrict__ cp) {
    __shared__ __align__(16) u16 Qs0[64 * 32];
    __shared__ __align__(16) u16 Qs1[64 * 32];
    const int t = threadIdx.x;
    const int wave = t >> 6;
    const int lane = t & 63;
    const int l32 = lane & 31, half = lane >> 5;
    const int qchunk = blockIdx.x & 1;
    const int kblk = (blockIdx.x >> 1) & 15;
    const int bh = blockIdx.x >> 5;
    const int k0 = kblk * 128 + wave * 32;

    // persistent K fragments: B[n=l32][k=f*16+half*8+j]
    const u16* Kr = kb + (size_t)(bh * 2048 + k0 + l32) * 64 + half * 8;
    bf16x8 b[4];
#pragma unroll
    for (int f = 0; f < 4; f++) b[f] = *(const bf16x8*)&Kr[f * 16];

    const u16* Qbase = qb + (size_t)(bh * 2048 + qchunk * 1024) * 64;
    const float* li_b = li_ws + bh * 2048 + qchunk * 1024;
    const int srow = t >> 2, sc = (t & 3) * 8;

    float cs = 0.f;

    for (int qt = 0; qt < 16; qt++) {
        const u16* src = Qbase + (size_t)(qt * 64 + srow) * 64 + sc;
        async_copy16(src, &Qs0[t * 8]);
        async_copy16(src + 32, &Qs1[t * 8]);
        __syncthreads();
#pragma unroll
        for (int sub = 0; sub < 2; sub++) {
            const int row = sub * 32 + l32;
            bf16x8 af[4];
            af[0] = *(const bf16x8*)&Qs0[row * 32 + half * 8];
            af[1] = *(const bf16x8*)&Qs0[row * 32 + 16 + half * 8];
            af[2] = *(const bf16x8*)&Qs1[row * 32 + half * 8];
            af[3] = *(const bf16x8*)&Qs1[row * 32 + 16 + half * 8];
            f32x16 acc;
#pragma unroll
            for (int r = 0; r < 16; r++) acc[r] = 0.f;
#pragma unroll
            for (int f = 0; f < 4; f++)
                acc = __builtin_amdgcn_mfma_f32_32x32x16_bf16(af[f], b[f], acc, 0, 0, 0);
            const float* lr = li_b + qt * 64 + sub * 32 + half * 4;
            f32x4 li0 = *(const f32x4*)&lr[0];
            f32x4 li1 = *(const f32x4*)&lr[8];
            f32x4 li2 = *(const f32x4*)&lr[16];
            f32x4 li3 = *(const f32x4*)&lr[24];
#pragma unroll
            for (int r = 0; r < 4; r++) cs += __builtin_amdgcn_exp2f(acc[r]) * li0[r];
#pragma unroll
            for (int r = 0; r < 4; r++) cs += __builtin_amdgcn_exp2f(acc[4 + r]) * li1[r];
#pragma unroll
            for (int r = 0; r < 4; r++) cs += __builtin_amdgcn_exp2f(acc[8 + r]) * li2[r];
#pragma unroll
            for (int r = 0; r < 4; r++) cs += __builtin_amdgcn_exp2f(acc[12 + r]) * li3[r];
        }
        __syncthreads();
    }
    cs += __shfl_xor(cs, 32);
    if (lane < 32)
        cp[qchunk * 65536 + bh * 2048 + k0 + lane] = cs;
}

// values[b][s][h*64+d] = colsum[bh][s] * v[bh][s][d]  (bf16); sums 2 partials
__global__ __launch_bounds__(256) void scale_v(
    const u16* __restrict__ vb, const float* __restrict__ cp,
    u16* __restrict__ valsb) {
    int tid = blockIdx.x * 256 + threadIdx.x;  // 524288 threads, 8 elems each
    int base = tid << 3;
    int bh = base >> 17;           // / (2048*64)
    int rem = base & 131071;
    int s = rem >> 6;
    int d0 = rem & 63;
    int ci = bh * 2048 + s;
    float cs = cp[ci] + cp[65536 + ci];
    u16x8 v = *(const u16x8*)(vb + (size_t)base);
    u16x8 o;
#pragma unroll
    for (int i = 0; i < 8; i++) o[i] = f2bf(bf2f(v[i]) * cs);
    int b = bh >> 4, h = bh & 15;
    *(u16x8*)(valsb + (size_t)((b * 2048 + s) * 1024) + h * 64 + d0) = o;
}

// ---------------- launch ----------------

extern "C" void kernel_launch(void* const* d_in, const int* in_sizes, int n_in,
                              void* d_out, int out_size, void* d_ws, size_t ws_size,
                              hipStream_t stream) {
    const float* x    = (const float*)d_in[0];   // [2,2048,1024]
    const float* wqkv = (const float*)d_in[1];   // [1024,3072]
    const float* wo   = (const float*)d_in[2];   // [1024,1024]
    float* out = (float*)d_out;                  // [2,2048,1024] fp32
    char* ws = (char*)d_ws;

    u16* xb      = (u16*)(ws);                   // [4096][1024] bf16 (dead after gemm_qkv)
    u16* wqkvT   = (u16*)(ws + 8388608);         // [3072][1024] bf16
    u16* woT     = (u16*)(ws + 14680064);        // [1024][1024] bf16
    u16* qb      = (u16*)(ws + 16777216);        // [32][2048][64] bf16
    u16* kb      = (u16*)(ws + 25165824);
    u16* vb      = (u16*)(ws + 33554432);
    float* li_ws = (float*)(ws + 41943040);      // [32][2048]
    u16* valsb   = (u16*)(ws + 42467328);        // [4096][1024] bf16
    // partial buffers alias xb (dead after gemm_qkv): 2 x 512KB
    float* lp    = (float*)(ws);                 // [2][32][2048]
    float* cp    = (float*)(ws + 1048576);       // [2][32][2048]

    cast_f32_bf16<<<4096, 256, 0, stream>>>(x, xb, 1048576);
    transpose_cast<<<dim3(96, 32), dim3(32, 8), 0, stream>>>(wqkv, wqkvT, 1024, 3072);
    transpose_cast<<<dim3(32, 32), dim3(32, 8), 0, stream>>>(wo, woT, 1024, 1024);
    gemm_qkv<<<dim3(24, 32), 256, 0, stream>>>(xb, wqkvT, qb, kb, vb);
    attn_pass1<<<1024, 256, 0, stream>>>(qb, kb, lp);
    reduce_li<<<256, 256, 0, stream>>>(lp, li_ws);
    attn_pass2<<<1024, 256, 0, stream>>>(qb, kb, li_ws, cp);
    scale_v<<<2048, 256, 0, stream>>>(vb, cp, valsb);
    gemm_out<<<dim3(8, 32), 256, 0, stream>>>(valsb, woT, out);
}

// Round 6
// 200.512 us; speedup vs baseline: 1.4951x; 1.0436x over previous
//
#include <hip/hip_runtime.h>
#include <stdint.h>

// Problem constants: B=2, S=2048, HIDDEN=1024, NH=16, D=64
// M = B*S = 4096, N1 = 3072, K = 1024, N2 = 1024, BH = 32

#define DEV static __device__ __forceinline__

typedef unsigned short u16;
typedef __attribute__((ext_vector_type(4))) float f32x4;
typedef __attribute__((ext_vector_type(16))) float f32x16;
typedef __bf16 bf16x8 __attribute__((ext_vector_type(8)));
typedef __attribute__((ext_vector_type(8))) unsigned short u16x8;
typedef __attribute__((ext_vector_type(4))) unsigned short u16x4;

// 0.125 * log2(e): folded into Q so softmax weights are exp2(acc)
#define QSCALE 0.18033688011112042f

DEV u16 f2bf(float f) {
    unsigned u = __builtin_bit_cast(unsigned, f);
    u += 0x7fffu + ((u >> 16) & 1u);
    return (u16)(u >> 16);
}
DEV float bf2f(u16 h) {
    unsigned u = ((unsigned)h) << 16;
    return __builtin_bit_cast(float, u);
}

// async global->LDS, 16B per lane. LDS dest must be wave-uniform base + lane*16.
DEV void async_copy16(const void* g, void* l) {
    __builtin_amdgcn_global_load_lds(
        (__attribute__((address_space(1))) void*)(g),
        (__attribute__((address_space(3))) void*)(l), 16, 0, 0);
}

// ---------------- elementwise cast kernels ----------------

__global__ __launch_bounds__(256) void cast_f32_bf16(
    const float* __restrict__ src, u16* __restrict__ dst, int n4) {
    int i = blockIdx.x * 256 + threadIdx.x;
    if (i >= n4) return;
    f32x4 v = *(const f32x4*)(src + (size_t)i * 4);
    u16x4 o;
#pragma unroll
    for (int j = 0; j < 4; j++) o[j] = f2bf(v[j]);
    *(u16x4*)(dst + (size_t)i * 4) = o;
}

// src [rows][cols] fp32  ->  dst [cols][rows] bf16
__global__ __launch_bounds__(256) void transpose_cast(
    const float* __restrict__ src, u16* __restrict__ dst, int rows, int cols) {
    __shared__ float tile[32][33];
    int c0 = blockIdx.x * 32, r0 = blockIdx.y * 32;
    int tx = threadIdx.x, ty = threadIdx.y;  // block (32,8)
#pragma unroll
    for (int i = 0; i < 4; i++)
        tile[ty + i * 8][tx] = src[(size_t)(r0 + ty + i * 8) * cols + c0 + tx];
    __syncthreads();
#pragma unroll
    for (int i = 0; i < 4; i++)
        dst[(size_t)(c0 + ty + i * 8) * rows + r0 + tx] = f2bf(tile[tx][ty + i * 8]);
}

// ---------------- 128x128 bf16 MFMA GEMM core ----------------
DEV void gemm128_core(const u16* __restrict__ A, const u16* __restrict__ Bt,
                      int m0, int n0, int Kdim, u16* As, u16* Bs,
                      f32x4 (*acc)[4]) {
    const int t = threadIdx.x;
    const int wave = t >> 6;
    const int lane = t & 63;
    const int quad = lane >> 4;
    const int l16 = lane & 15;
    const int wr = wave >> 1;
    const int wc = wave & 1;

    for (int kt = 0; kt < Kdim; kt += 32) {
#pragma unroll
        for (int i = 0; i < 2; i++) {
            int idx = i * 256 + t;
            int row = idx >> 2, kc = idx & 3;
            async_copy16(A + (size_t)(m0 + row) * Kdim + kt + kc * 8, &As[idx * 8]);
            async_copy16(Bt + (size_t)(n0 + row) * Kdim + kt + kc * 8, &Bs[idx * 8]);
        }
        __syncthreads();
        bf16x8 af[4], bfr[4];
#pragma unroll
        for (int mt = 0; mt < 4; mt++)
            af[mt] = *(const bf16x8*)&As[(wr * 64 + mt * 16 + l16) * 32 + quad * 8];
#pragma unroll
        for (int nt = 0; nt < 4; nt++)
            bfr[nt] = *(const bf16x8*)&Bs[(wc * 64 + nt * 16 + l16) * 32 + quad * 8];
#pragma unroll
        for (int mt = 0; mt < 4; mt++)
#pragma unroll
            for (int nt = 0; nt < 4; nt++)
                acc[mt][nt] = __builtin_amdgcn_mfma_f32_16x16x32_bf16(
                    af[mt], bfr[nt], acc[mt][nt], 0, 0, 0);
        __syncthreads();
    }
}

// GEMM1: qkv projection, epilogue scatters into q/k/v [bh][s][d] bf16.
__global__ __launch_bounds__(256) void gemm_qkv(
    const u16* __restrict__ A, const u16* __restrict__ Bt,
    u16* __restrict__ qb, u16* __restrict__ kb, u16* __restrict__ vb) {
    __shared__ __align__(16) u16 As[128 * 32];
    __shared__ __align__(16) u16 Bs[128 * 32];
    const int m0 = blockIdx.y * 128;
    const int n0 = blockIdx.x * 128;
    f32x4 acc[4][4];
#pragma unroll
    for (int i = 0; i < 4; i++)
#pragma unroll
        for (int j = 0; j < 4; j++) acc[i][j] = {0.f, 0.f, 0.f, 0.f};

    gemm128_core(A, Bt, m0, n0, 1024, As, Bs, acc);

    const int t = threadIdx.x;
    const int wave = t >> 6, lane = t & 63;
    const int quad = lane >> 4, l16 = lane & 15;
    const int wr = wave >> 1, wc = wave & 1;
#pragma unroll
    for (int nt = 0; nt < 4; nt++) {
        int nn = n0 + wc * 64 + nt * 16 + l16;
        int tsel = nn >> 10;           // 0=q 1=k 2=v
        int rem = nn & 1023;
        int h = rem >> 6, d = rem & 63;
        u16* dst = tsel == 0 ? qb : (tsel == 1 ? kb : vb);
        float scl = tsel == 0 ? QSCALE : 1.0f;
#pragma unroll
        for (int mt = 0; mt < 4; mt++) {
#pragma unroll
            for (int r = 0; r < 4; r++) {
                int mm = m0 + wr * 64 + mt * 16 + quad * 4 + r;
                int b = mm >> 11, s = mm & 2047;
                dst[(size_t)((b * 16 + h) * 2048 + s) * 64 + d] = f2bf(acc[mt][nt][r] * scl);
            }
        }
    }
}

// GEMM2: out = values @ w_o, fp32 output. 64x128 tiles -> 512 blocks (2/CU)
// so a co-resident block covers each barrier drain.
__global__ __launch_bounds__(256) void gemm_out(
    const u16* __restrict__ A, const u16* __restrict__ Bt,
    float* __restrict__ out) {
    __shared__ __align__(16) u16 As[64 * 32];
    __shared__ __align__(16) u16 Bs[128 * 32];
    const int m0 = blockIdx.y * 64;
    const int n0 = blockIdx.x * 128;
    const int t = threadIdx.x;
    const int wave = t >> 6, lane = t & 63;
    const int quad = lane >> 4, l16 = lane & 15;
    const int wr = wave >> 1, wc = wave & 1;  // wave tile: 32 rows x 64 cols

    f32x4 acc[2][4];
#pragma unroll
    for (int i = 0; i < 2; i++)
#pragma unroll
        for (int j = 0; j < 4; j++) acc[i][j] = {0.f, 0.f, 0.f, 0.f};

    for (int kt = 0; kt < 1024; kt += 32) {
        async_copy16(A + (size_t)(m0 + (t >> 2)) * 1024 + kt + (t & 3) * 8, &As[t * 8]);
#pragma unroll
        for (int i = 0; i < 2; i++) {
            int idx = i * 256 + t;
            int row = idx >> 2, kc = idx & 3;
            async_copy16(Bt + (size_t)(n0 + row) * 1024 + kt + kc * 8, &Bs[idx * 8]);
        }
        __syncthreads();
        bf16x8 af[2], bfr[4];
#pragma unroll
        for (int mt = 0; mt < 2; mt++)
            af[mt] = *(const bf16x8*)&As[(wr * 32 + mt * 16 + l16) * 32 + quad * 8];
#pragma unroll
        for (int nt = 0; nt < 4; nt++)
            bfr[nt] = *(const bf16x8*)&Bs[(wc * 64 + nt * 16 + l16) * 32 + quad * 8];
#pragma unroll
        for (int mt = 0; mt < 2; mt++)
#pragma unroll
            for (int nt = 0; nt < 4; nt++)
                acc[mt][nt] = __builtin_amdgcn_mfma_f32_16x16x32_bf16(
                    af[mt], bfr[nt], acc[mt][nt], 0, 0, 0);
        __syncthreads();
    }
#pragma unroll
    for (int nt = 0; nt < 4; nt++) {
        int nn = n0 + wc * 64 + nt * 16 + l16;
#pragma unroll
        for (int mt = 0; mt < 2; mt++) {
#pragma unroll
            for (int r = 0; r < 4; r++) {
                int mm = m0 + wr * 32 + mt * 16 + quad * 4 + r;
                out[(size_t)mm * 1024 + nn] = acc[mt][nt][r];
            }
        }
    }
}

// ---------------- attention passes (LDS-staged, 128 rows per barrier) -------
// No max subtraction: scores are O(+-5); exp(s)/sum(exp(s)) == softmax.
// Q pre-scaled by 0.125*log2e so weights are exp2(acc).
// 32x32x16 layouts: A/B [row=lane&31][k=f*16+(lane>>5)*8+j];
// C/D col=lane&31, row=(r&3)+8*(r>>2)+4*(lane>>5).
//
// Pass 1: block = 4 waves x 32 q-rows = 128 q-rows; stages 128 k-rows
// (16 KB) per barrier pair, 8 iterations over its 1024-k chunk.
__global__ __launch_bounds__(256) void attn_pass1(
    const u16* __restrict__ qb, const u16* __restrict__ kb,
    float* __restrict__ lp) {
    __shared__ __align__(16) u16 Ks0[128 * 32];  // d 0..31
    __shared__ __align__(16) u16 Ks1[128 * 32];  // d 32..63
    const int t = threadIdx.x;
    const int wave = t >> 6;
    const int lane = t & 63;
    const int l32 = lane & 31, half = lane >> 5;
    const int kchunk = blockIdx.x & 1;
    const int qblk = (blockIdx.x >> 1) & 15;
    const int bh = blockIdx.x >> 5;
    const int q0 = qblk * 128 + wave * 32;

    // persistent Q fragments: A[m=l32][k=f*16+half*8+j]
    const u16* Qr = qb + (size_t)(bh * 2048 + q0 + l32) * 64 + half * 8;
    bf16x8 a[4];
#pragma unroll
    for (int f = 0; f < 4; f++) a[f] = *(const bf16x8*)&Qr[f * 16];

    const u16* Kbase = kb + (size_t)(bh * 2048 + kchunk * 1024) * 64;
    const int srow = t >> 2, sc = (t & 3) * 8;

    float lsum[16];
#pragma unroll
    for (int r = 0; r < 16; r++) lsum[r] = 0.f;

    for (int kt = 0; kt < 8; kt++) {
#pragma unroll
        for (int rr = 0; rr < 2; rr++) {
            const u16* src = Kbase + (size_t)(kt * 128 + rr * 64 + srow) * 64 + sc;
            async_copy16(src, &Ks0[rr * 2048 + t * 8]);
            async_copy16(src + 32, &Ks1[rr * 2048 + t * 8]);
        }
        __syncthreads();
#pragma unroll
        for (int sub = 0; sub < 4; sub++) {
            const int row = sub * 32 + l32;
            bf16x8 bfr[4];
            bfr[0] = *(const bf16x8*)&Ks0[row * 32 + half * 8];
            bfr[1] = *(const bf16x8*)&Ks0[row * 32 + 16 + half * 8];
            bfr[2] = *(const bf16x8*)&Ks1[row * 32 + half * 8];
            bfr[3] = *(const bf16x8*)&Ks1[row * 32 + 16 + half * 8];
            f32x16 acc;
#pragma unroll
            for (int r = 0; r < 16; r++) acc[r] = 0.f;
#pragma unroll
            for (int f = 0; f < 4; f++)
                acc = __builtin_amdgcn_mfma_f32_32x32x16_bf16(a[f], bfr[f], acc, 0, 0, 0);
#pragma unroll
            for (int r = 0; r < 16; r++)
                lsum[r] += __builtin_amdgcn_exp2f(acc[r]);
        }
        __syncthreads();
    }
    // reduce each row across the 32 k-columns (lanes within each half)
#pragma unroll
    for (int r = 0; r < 16; r++) {
        float v = lsum[r];
        v += __shfl_xor(v, 1);
        v += __shfl_xor(v, 2);
        v += __shfl_xor(v, 4);
        v += __shfl_xor(v, 8);
        v += __shfl_xor(v, 16);
        lsum[r] = v;
    }
    if (l32 == 0) {
        float* dst = lp + kchunk * 65536 + bh * 2048 + q0 + half * 4;
#pragma unroll
        for (int r = 0; r < 16; r++)
            dst[(r & 3) + 8 * (r >> 2)] = lsum[r];
    }
}

// Pass 2: block = 4 waves x 32 k-cols = 128 k-cols; stages 128 q-rows per
// barrier pair; li = 1/(lp0+lp1) computed once into LDS at block start.
__global__ __launch_bounds__(256) void attn_pass2(
    const u16* __restrict__ qb, const u16* __restrict__ kb,
    const float* __restrict__ lp, float* __restrict__ cp) {
    __shared__ __align__(16) u16 Qs0[128 * 32];
    __shared__ __align__(16) u16 Qs1[128 * 32];
    __shared__ __align__(16) float li_lds[1024];
    const int t = threadIdx.x;
    const int wave = t >> 6;
    const int lane = t & 63;
    const int l32 = lane & 31, half = lane >> 5;
    const int qchunk = blockIdx.x & 1;
    const int kblk = (blockIdx.x >> 1) & 15;
    const int bh = blockIdx.x >> 5;
    const int k0 = kblk * 128 + wave * 32;

    // li table for this block's q-chunk
    {
        const int base = bh * 2048 + qchunk * 1024;
        f32x4 p0 = *(const f32x4*)&lp[base + t * 4];
        f32x4 p1 = *(const f32x4*)&lp[65536 + base + t * 4];
        f32x4 li;
#pragma unroll
        for (int j = 0; j < 4; j++) li[j] = 1.0f / (p0[j] + p1[j]);
        *(f32x4*)&li_lds[t * 4] = li;
    }

    // persistent K fragments: B[n=l32][k=f*16+half*8+j]
    const u16* Kr = kb + (size_t)(bh * 2048 + k0 + l32) * 64 + half * 8;
    bf16x8 b[4];
#pragma unroll
    for (int f = 0; f < 4; f++) b[f] = *(const bf16x8*)&Kr[f * 16];

    const u16* Qbase = qb + (size_t)(bh * 2048 + qchunk * 1024) * 64;
    const int srow = t >> 2, sc = (t & 3) * 8;

    float cs = 0.f;
    __syncthreads();  // li_lds ready

    for (int qt = 0; qt < 8; qt++) {
#pragma unroll
        for (int rr = 0; rr < 2; rr++) {
            const u16* src = Qbase + (size_t)(qt * 128 + rr * 64 + srow) * 64 + sc;
            async_copy16(src, &Qs0[rr * 2048 + t * 8]);
            async_copy16(src + 32, &Qs1[rr * 2048 + t * 8]);
        }
        __syncthreads();
#pragma unroll
        for (int sub = 0; sub < 4; sub++) {
            const int row = sub * 32 + l32;
            bf16x8 af[4];
            af[0] = *(const bf16x8*)&Qs0[row * 32 + half * 8];
            af[1] = *(const bf16x8*)&Qs0[row * 32 + 16 + half * 8];
            af[2] = *(const bf16x8*)&Qs1[row * 32 + half * 8];
            af[3] = *(const bf16x8*)&Qs1[row * 32 + 16 + half * 8];
            f32x16 acc;
#pragma unroll
            for (int r = 0; r < 16; r++) acc[r] = 0.f;
#pragma unroll
            for (int f = 0; f < 4; f++)
                acc = __builtin_amdgcn_mfma_f32_32x32x16_bf16(af[f], b[f], acc, 0, 0, 0);
            const float* lr = &li_lds[qt * 128 + sub * 32 + half * 4];
            f32x4 li0 = *(const f32x4*)&lr[0];
            f32x4 li1 = *(const f32x4*)&lr[8];
            f32x4 li2 = *(const f32x4*)&lr[16];
            f32x4 li3 = *(const f32x4*)&lr[24];
#pragma unroll
            for (int r = 0; r < 4; r++) cs += __builtin_amdgcn_exp2f(acc[r]) * li0[r];
#pragma unroll
            for (int r = 0; r < 4; r++) cs += __builtin_amdgcn_exp2f(acc[4 + r]) * li1[r];
#pragma unroll
            for (int r = 0; r < 4; r++) cs += __builtin_amdgcn_exp2f(acc[8 + r]) * li2[r];
#pragma unroll
            for (int r = 0; r < 4; r++) cs += __builtin_amdgcn_exp2f(acc[12 + r]) * li3[r];
        }
        __syncthreads();
    }
    cs += __shfl_xor(cs, 32);
    if (lane < 32)
        cp[qchunk * 65536 + bh * 2048 + k0 + lane] = cs;
}

// values[b][s][h*64+d] = colsum[bh][s] * v[bh][s][d]  (bf16); sums 2 partials
__global__ __launch_bounds__(256) void scale_v(
    const u16* __restrict__ vb, const float* __restrict__ cp,
    u16* __restrict__ valsb) {
    int tid = blockIdx.x * 256 + threadIdx.x;  // 524288 threads, 8 elems each
    int base = tid << 3;
    int bh = base >> 17;           // / (2048*64)
    int rem = base & 131071;
    int s = rem >> 6;
    int d0 = rem & 63;
    int ci = bh * 2048 + s;
    float cs = cp[ci] + cp[65536 + ci];
    u16x8 v = *(const u16x8*)(vb + (size_t)base);
    u16x8 o;
#pragma unroll
    for (int i = 0; i < 8; i++) o[i] = f2bf(bf2f(v[i]) * cs);
    int b = bh >> 4, h = bh & 15;
    *(u16x8*)(valsb + (size_t)((b * 2048 + s) * 1024) + h * 64 + d0) = o;
}

// ---------------- launch ----------------

extern "C" void kernel_launch(void* const* d_in, const int* in_sizes, int n_in,
                              void* d_out, int out_size, void* d_ws, size_t ws_size,
                              hipStream_t stream) {
    const float* x    = (const float*)d_in[0];   // [2,2048,1024]
    const float* wqkv = (const float*)d_in[1];   // [1024,3072]
    const float* wo   = (const float*)d_in[2];   // [1024,1024]
    float* out = (float*)d_out;                  // [2,2048,1024] fp32
    char* ws = (char*)d_ws;

    u16* xb      = (u16*)(ws);                   // [4096][1024] bf16 (dead after gemm_qkv)
    u16* wqkvT   = (u16*)(ws + 8388608);         // [3072][1024] bf16
    u16* woT     = (u16*)(ws + 14680064);        // [1024][1024] bf16
    u16* qb      = (u16*)(ws + 16777216);        // [32][2048][64] bf16
    u16* kb      = (u16*)(ws + 25165824);
    u16* vb      = (u16*)(ws + 33554432);
    u16* valsb   = (u16*)(ws + 42467328);        // [4096][1024] bf16
    // partial buffers alias xb (dead after gemm_qkv)
    float* lp    = (float*)(ws);                 // [2][32][2048]
    float* cp    = (float*)(ws + 1048576);       // [2][32][2048]

    cast_f32_bf16<<<4096, 256, 0, stream>>>(x, xb, 1048576);
    transpose_cast<<<dim3(96, 32), dim3(32, 8), 0, stream>>>(wqkv, wqkvT, 1024, 3072);
    transpose_cast<<<dim3(32, 32), dim3(32, 8), 0, stream>>>(wo, woT, 1024, 1024);
    gemm_qkv<<<dim3(24, 32), 256, 0, stream>>>(xb, wqkvT, qb, kb, vb);
    attn_pass1<<<1024, 256, 0, stream>>>(qb, kb, lp);
    attn_pass2<<<1024, 256, 0, stream>>>(qb, kb, lp, cp);
    scale_v<<<2048, 256, 0, stream>>>(vb, cp, valsb);
    gemm_out<<<dim3(8, 64), 256, 0, stream>>>(valsb, woT, out);
}

// Round 7
// 198.571 us; speedup vs baseline: 1.5097x; 1.0098x over previous
//
#include <hip/hip_runtime.h>
#include <stdint.h>

// Problem constants: B=2, S=2048, HIDDEN=1024, NH=16, D=64
// M = B*S = 4096, N1 = 3072, K = 1024, N2 = 1024, BH = 32

#define DEV static __device__ __forceinline__

typedef unsigned short u16;
typedef __attribute__((ext_vector_type(4))) float f32x4;
typedef __attribute__((ext_vector_type(16))) float f32x16;
typedef __bf16 bf16x8 __attribute__((ext_vector_type(8)));
typedef __attribute__((ext_vector_type(8))) unsigned short u16x8;
typedef __attribute__((ext_vector_type(4))) unsigned short u16x4;

// 0.125 * log2(e): folded into Q so softmax weights are exp2(acc)
#define QSCALE 0.18033688011112042f

DEV u16 f2bf(float f) {
    unsigned u = __builtin_bit_cast(unsigned, f);
    u += 0x7fffu + ((u >> 16) & 1u);
    return (u16)(u >> 16);
}
DEV float bf2f(u16 h) {
    unsigned u = ((unsigned)h) << 16;
    return __builtin_bit_cast(float, u);
}

// async global->LDS, 16B per lane. LDS dest must be wave-uniform base + lane*16.
DEV void async_copy16(const void* g, void* l) {
    __builtin_amdgcn_global_load_lds(
        (__attribute__((address_space(1))) void*)(g),
        (__attribute__((address_space(3))) void*)(l), 16, 0, 0);
}

// ---------------- elementwise cast kernels ----------------

__global__ __launch_bounds__(256) void cast_f32_bf16(
    const float* __restrict__ src, u16* __restrict__ dst, int n4) {
    int i = blockIdx.x * 256 + threadIdx.x;
    if (i >= n4) return;
    f32x4 v = *(const f32x4*)(src + (size_t)i * 4);
    u16x4 o;
#pragma unroll
    for (int j = 0; j < 4; j++) o[j] = f2bf(v[j]);
    *(u16x4*)(dst + (size_t)i * 4) = o;
}

// src [rows][cols] fp32  ->  dst [cols][rows] bf16
__global__ __launch_bounds__(256) void transpose_cast(
    const float* __restrict__ src, u16* __restrict__ dst, int rows, int cols) {
    __shared__ float tile[32][33];
    int c0 = blockIdx.x * 32, r0 = blockIdx.y * 32;
    int tx = threadIdx.x, ty = threadIdx.y;  // block (32,8)
#pragma unroll
    for (int i = 0; i < 4; i++)
        tile[ty + i * 8][tx] = src[(size_t)(r0 + ty + i * 8) * cols + c0 + tx];
    __syncthreads();
#pragma unroll
    for (int i = 0; i < 4; i++)
        dst[(size_t)(c0 + ty + i * 8) * rows + r0 + tx] = f2bf(tile[tx][ty + i * 8]);
}

// ---------------- GEMM1: qkv projection ----------------
// 128x128 tile; LDS-transpose epilogue -> coalesced 16B stores into
// q/k/v [bh][s][d] bf16. n-range of each block lies in exactly one of
// q/k/v (n0 multiple of 128, sections are 1024-wide), so dst/scale are
// block-uniform.
__global__ __launch_bounds__(256) void gemm_qkv(
    const u16* __restrict__ A, const u16* __restrict__ Bt,
    u16* __restrict__ qb, u16* __restrict__ kb, u16* __restrict__ vb) {
    __shared__ __align__(16) u16 smem[128 * 136];  // 34 KB; aliases As/Bs/Cs
    u16* As = smem;            // [128][32]
    u16* Bs = smem + 4096;     // [128][32]
    const int t = threadIdx.x;
    const int wave = t >> 6;
    const int lane = t & 63;
    const int quad = lane >> 4;
    const int l16 = lane & 15;
    const int wr = wave >> 1;
    const int wc = wave & 1;
    const int m0 = blockIdx.y * 128;
    const int n0 = blockIdx.x * 128;

    f32x4 acc[4][4];
#pragma unroll
    for (int i = 0; i < 4; i++)
#pragma unroll
        for (int j = 0; j < 4; j++) acc[i][j] = {0.f, 0.f, 0.f, 0.f};

    for (int kt = 0; kt < 1024; kt += 32) {
#pragma unroll
        for (int i = 0; i < 2; i++) {
            int idx = i * 256 + t;
            int row = idx >> 2, kc = idx & 3;
            async_copy16(A + (size_t)(m0 + row) * 1024 + kt + kc * 8, &As[idx * 8]);
            async_copy16(Bt + (size_t)(n0 + row) * 1024 + kt + kc * 8, &Bs[idx * 8]);
        }
        __syncthreads();
        bf16x8 af[4], bfr[4];
#pragma unroll
        for (int mt = 0; mt < 4; mt++)
            af[mt] = *(const bf16x8*)&As[(wr * 64 + mt * 16 + l16) * 32 + quad * 8];
#pragma unroll
        for (int nt = 0; nt < 4; nt++)
            bfr[nt] = *(const bf16x8*)&Bs[(wc * 64 + nt * 16 + l16) * 32 + quad * 8];
#pragma unroll
        for (int mt = 0; mt < 4; mt++)
#pragma unroll
            for (int nt = 0; nt < 4; nt++)
                acc[mt][nt] = __builtin_amdgcn_mfma_f32_16x16x32_bf16(
                    af[mt], bfr[nt], acc[mt][nt], 0, 0, 0);
        __syncthreads();
    }

    // ---- epilogue: acc -> LDS [m][n] bf16 (stride 136) -> coalesced global
    const int tsel = n0 >> 10;  // 0=q 1=k 2=v (block-uniform)
    u16* dst = tsel == 0 ? qb : (tsel == 1 ? kb : vb);
    const float scl = tsel == 0 ? QSCALE : 1.0f;
#pragma unroll
    for (int mt = 0; mt < 4; mt++)
#pragma unroll
        for (int nt = 0; nt < 4; nt++) {
            int nn = wc * 64 + nt * 16 + l16;
#pragma unroll
            for (int r = 0; r < 4; r++) {
                int mm = wr * 64 + mt * 16 + quad * 4 + r;
                smem[mm * 136 + nn] = f2bf(acc[mt][nt][r] * scl);
            }
        }
    __syncthreads();
    const int col0 = (l16) * 8;       // 0..120, within one 64-d head (8-aligned)
    const int rowb = (t >> 4);        // 0..15
    const int h0 = (n0 & 1023) >> 6;  // first of the block's 2 heads
#pragma unroll
    for (int i = 0; i < 8; i++) {
        int row = i * 16 + rowb;      // 0..127
        u16x8 v = *(const u16x8*)&smem[row * 136 + col0];
        int h = h0 + (col0 >> 6), d = col0 & 63;
        int mm = m0 + row;
        int b = mm >> 11, s = mm & 2047;
        *(u16x8*)&dst[((size_t)((b * 16 + h) * 2048 + s)) * 64 + d] = v;
    }
}

// GEMM2: out = values @ w_o, fp32 output. 64x128 tiles -> 512 blocks (2/CU)
// so a co-resident block covers each barrier drain.
__global__ __launch_bounds__(256) void gemm_out(
    const u16* __restrict__ A, const u16* __restrict__ Bt,
    float* __restrict__ out) {
    __shared__ __align__(16) u16 As[64 * 32];
    __shared__ __align__(16) u16 Bs[128 * 32];
    const int m0 = blockIdx.y * 64;
    const int n0 = blockIdx.x * 128;
    const int t = threadIdx.x;
    const int wave = t >> 6, lane = t & 63;
    const int quad = lane >> 4, l16 = lane & 15;
    const int wr = wave >> 1, wc = wave & 1;  // wave tile: 32 rows x 64 cols

    f32x4 acc[2][4];
#pragma unroll
    for (int i = 0; i < 2; i++)
#pragma unroll
        for (int j = 0; j < 4; j++) acc[i][j] = {0.f, 0.f, 0.f, 0.f};

    for (int kt = 0; kt < 1024; kt += 32) {
        async_copy16(A + (size_t)(m0 + (t >> 2)) * 1024 + kt + (t & 3) * 8, &As[t * 8]);
#pragma unroll
        for (int i = 0; i < 2; i++) {
            int idx = i * 256 + t;
            int row = idx >> 2, kc = idx & 3;
            async_copy16(Bt + (size_t)(n0 + row) * 1024 + kt + kc * 8, &Bs[idx * 8]);
        }
        __syncthreads();
        bf16x8 af[2], bfr[4];
#pragma unroll
        for (int mt = 0; mt < 2; mt++)
            af[mt] = *(const bf16x8*)&As[(wr * 32 + mt * 16 + l16) * 32 + quad * 8];
#pragma unroll
        for (int nt = 0; nt < 4; nt++)
            bfr[nt] = *(const bf16x8*)&Bs[(wc * 64 + nt * 16 + l16) * 32 + quad * 8];
#pragma unroll
        for (int mt = 0; mt < 2; mt++)
#pragma unroll
            for (int nt = 0; nt < 4; nt++)
                acc[mt][nt] = __builtin_amdgcn_mfma_f32_16x16x32_bf16(
                    af[mt], bfr[nt], acc[mt][nt], 0, 0, 0);
        __syncthreads();
    }
#pragma unroll
    for (int nt = 0; nt < 4; nt++) {
        int nn = n0 + wc * 64 + nt * 16 + l16;
#pragma unroll
        for (int mt = 0; mt < 2; mt++) {
#pragma unroll
            for (int r = 0; r < 4; r++) {
                int mm = m0 + wr * 32 + mt * 16 + quad * 4 + r;
                out[(size_t)mm * 1024 + nn] = acc[mt][nt][r];
            }
        }
    }
}

// ---------------- attention passes (LDS-staged, 128 rows per barrier) -------
// No max subtraction: scores are O(+-5); exp(s)/sum(exp(s)) == softmax.
// Q pre-scaled by 0.125*log2e so weights are exp2(acc).
// 32x32x16 layouts: A/B [row=lane&31][k=f*16+(lane>>5)*8+j];
// C/D col=lane&31, row=(r&3)+8*(r>>2)+4*(lane>>5).
//
// Pass 1: block = 4 waves x 32 q-rows = 128 q-rows; stages 128 k-rows
// (16 KB) per barrier pair, 8 iterations over its 1024-k chunk.
__global__ __launch_bounds__(256) void attn_pass1(
    const u16* __restrict__ qb, const u16* __restrict__ kb,
    float* __restrict__ lp) {
    __shared__ __align__(16) u16 Ks0[128 * 32];  // d 0..31
    __shared__ __align__(16) u16 Ks1[128 * 32];  // d 32..63
    const int t = threadIdx.x;
    const int wave = t >> 6;
    const int lane = t & 63;
    const int l32 = lane & 31, half = lane >> 5;
    const int kchunk = blockIdx.x & 1;
    const int qblk = (blockIdx.x >> 1) & 15;
    const int bh = blockIdx.x >> 5;
    const int q0 = qblk * 128 + wave * 32;

    // persistent Q fragments: A[m=l32][k=f*16+half*8+j]
    const u16* Qr = qb + (size_t)(bh * 2048 + q0 + l32) * 64 + half * 8;
    bf16x8 a[4];
#pragma unroll
    for (int f = 0; f < 4; f++) a[f] = *(const bf16x8*)&Qr[f * 16];

    const u16* Kbase = kb + (size_t)(bh * 2048 + kchunk * 1024) * 64;
    const int srow = t >> 2, sc = (t & 3) * 8;

    float lsum[16];
#pragma unroll
    for (int r = 0; r < 16; r++) lsum[r] = 0.f;

    for (int kt = 0; kt < 8; kt++) {
#pragma unroll
        for (int rr = 0; rr < 2; rr++) {
            const u16* src = Kbase + (size_t)(kt * 128 + rr * 64 + srow) * 64 + sc;
            async_copy16(src, &Ks0[rr * 2048 + t * 8]);
            async_copy16(src + 32, &Ks1[rr * 2048 + t * 8]);
        }
        __syncthreads();
#pragma unroll
        for (int sub = 0; sub < 4; sub++) {
            const int row = sub * 32 + l32;
            bf16x8 bfr[4];
            bfr[0] = *(const bf16x8*)&Ks0[row * 32 + half * 8];
            bfr[1] = *(const bf16x8*)&Ks0[row * 32 + 16 + half * 8];
            bfr[2] = *(const bf16x8*)&Ks1[row * 32 + half * 8];
            bfr[3] = *(const bf16x8*)&Ks1[row * 32 + 16 + half * 8];
            f32x16 acc;
#pragma unroll
            for (int r = 0; r < 16; r++) acc[r] = 0.f;
#pragma unroll
            for (int f = 0; f < 4; f++)
                acc = __builtin_amdgcn_mfma_f32_32x32x16_bf16(a[f], bfr[f], acc, 0, 0, 0);
#pragma unroll
            for (int r = 0; r < 16; r++)
                lsum[r] += __builtin_amdgcn_exp2f(acc[r]);
        }
        __syncthreads();
    }
    // reduce each row across the 32 k-columns (lanes within each half)
#pragma unroll
    for (int r = 0; r < 16; r++) {
        float v = lsum[r];
        v += __shfl_xor(v, 1);
        v += __shfl_xor(v, 2);
        v += __shfl_xor(v, 4);
        v += __shfl_xor(v, 8);
        v += __shfl_xor(v, 16);
        lsum[r] = v;
    }
    if (l32 == 0) {
        float* dst = lp + kchunk * 65536 + bh * 2048 + q0 + half * 4;
#pragma unroll
        for (int r = 0; r < 16; r++)
            dst[(r & 3) + 8 * (r >> 2)] = lsum[r];
    }
}

// Pass 2: block = 4 waves x 32 k-cols = 128 k-cols; stages 128 q-rows per
// barrier pair; li = 1/(lp0+lp1) computed once into LDS at block start.
__global__ __launch_bounds__(256) void attn_pass2(
    const u16* __restrict__ qb, const u16* __restrict__ kb,
    const float* __restrict__ lp, float* __restrict__ cp) {
    __shared__ __align__(16) u16 Qs0[128 * 32];
    __shared__ __align__(16) u16 Qs1[128 * 32];
    __shared__ __align__(16) float li_lds[1024];
    const int t = threadIdx.x;
    const int wave = t >> 6;
    const int lane = t & 63;
    const int l32 = lane & 31, half = lane >> 5;
    const int qchunk = blockIdx.x & 1;
    const int kblk = (blockIdx.x >> 1) & 15;
    const int bh = blockIdx.x >> 5;
    const int k0 = kblk * 128 + wave * 32;

    // li table for this block's q-chunk
    {
        const int base = bh * 2048 + qchunk * 1024;
        f32x4 p0 = *(const f32x4*)&lp[base + t * 4];
        f32x4 p1 = *(const f32x4*)&lp[65536 + base + t * 4];
        f32x4 li;
#pragma unroll
        for (int j = 0; j < 4; j++) li[j] = 1.0f / (p0[j] + p1[j]);
        *(f32x4*)&li_lds[t * 4] = li;
    }

    // persistent K fragments: B[n=l32][k=f*16+half*8+j]
    const u16* Kr = kb + (size_t)(bh * 2048 + k0 + l32) * 64 + half * 8;
    bf16x8 b[4];
#pragma unroll
    for (int f = 0; f < 4; f++) b[f] = *(const bf16x8*)&Kr[f * 16];

    const u16* Qbase = qb + (size_t)(bh * 2048 + qchunk * 1024) * 64;
    const int srow = t >> 2, sc = (t & 3) * 8;

    float cs = 0.f;
    __syncthreads();  // li_lds ready

    for (int qt = 0; qt < 8; qt++) {
#pragma unroll
        for (int rr = 0; rr < 2; rr++) {
            const u16* src = Qbase + (size_t)(qt * 128 + rr * 64 + srow) * 64 + sc;
            async_copy16(src, &Qs0[rr * 2048 + t * 8]);
            async_copy16(src + 32, &Qs1[rr * 2048 + t * 8]);
        }
        __syncthreads();
#pragma unroll
        for (int sub = 0; sub < 4; sub++) {
            const int row = sub * 32 + l32;
            bf16x8 af[4];
            af[0] = *(const bf16x8*)&Qs0[row * 32 + half * 8];
            af[1] = *(const bf16x8*)&Qs0[row * 32 + 16 + half * 8];
            af[2] = *(const bf16x8*)&Qs1[row * 32 + half * 8];
            af[3] = *(const bf16x8*)&Qs1[row * 32 + 16 + half * 8];
            f32x16 acc;
#pragma unroll
            for (int r = 0; r < 16; r++) acc[r] = 0.f;
#pragma unroll
            for (int f = 0; f < 4; f++)
                acc = __builtin_amdgcn_mfma_f32_32x32x16_bf16(af[f], b[f], acc, 0, 0, 0);
            const float* lr = &li_lds[qt * 128 + sub * 32 + half * 4];
            f32x4 li0 = *(const f32x4*)&lr[0];
            f32x4 li1 = *(const f32x4*)&lr[8];
            f32x4 li2 = *(const f32x4*)&lr[16];
            f32x4 li3 = *(const f32x4*)&lr[24];
#pragma unroll
            for (int r = 0; r < 4; r++) cs += __builtin_amdgcn_exp2f(acc[r]) * li0[r];
#pragma unroll
            for (int r = 0; r < 4; r++) cs += __builtin_amdgcn_exp2f(acc[4 + r]) * li1[r];
#pragma unroll
            for (int r = 0; r < 4; r++) cs += __builtin_amdgcn_exp2f(acc[8 + r]) * li2[r];
#pragma unroll
            for (int r = 0; r < 4; r++) cs += __builtin_amdgcn_exp2f(acc[12 + r]) * li3[r];
        }
        __syncthreads();
    }
    cs += __shfl_xor(cs, 32);
    if (lane < 32)
        cp[qchunk * 65536 + bh * 2048 + k0 + lane] = cs;
}

// values[b][s][h*64+d] = colsum[bh][s] * v[bh][s][d]  (bf16); sums 2 partials
__global__ __launch_bounds__(256) void scale_v(
    const u16* __restrict__ vb, const float* __restrict__ cp,
    u16* __restrict__ valsb) {
    int tid = blockIdx.x * 256 + threadIdx.x;  // 524288 threads, 8 elems each
    int base = tid << 3;
    int bh = base >> 17;           // / (2048*64)
    int rem = base & 131071;
    int s = rem >> 6;
    int d0 = rem & 63;
    int ci = bh * 2048 + s;
    float cs = cp[ci] + cp[65536 + ci];
    u16x8 v = *(const u16x8*)(vb + (size_t)base);
    u16x8 o;
#pragma unroll
    for (int i = 0; i < 8; i++) o[i] = f2bf(bf2f(v[i]) * cs);
    int b = bh >> 4, h = bh & 15;
    *(u16x8*)(valsb + (size_t)((b * 2048 + s) * 1024) + h * 64 + d0) = o;
}

// ---------------- launch ----------------

extern "C" void kernel_launch(void* const* d_in, const int* in_sizes, int n_in,
                              void* d_out, int out_size, void* d_ws, size_t ws_size,
                              hipStream_t stream) {
    const float* x    = (const float*)d_in[0];   // [2,2048,1024]
    const float* wqkv = (const float*)d_in[1];   // [1024,3072]
    const float* wo   = (const float*)d_in[2];   // [1024,1024]
    float* out = (float*)d_out;                  // [2,2048,1024] fp32
    char* ws = (char*)d_ws;

    u16* xb      = (u16*)(ws);                   // [4096][1024] bf16 (dead after gemm_qkv)
    u16* wqkvT   = (u16*)(ws + 8388608);         // [3072][1024] bf16
    u16* woT     = (u16*)(ws + 14680064);        // [1024][1024] bf16
    u16* qb      = (u16*)(ws + 16777216);        // [32][2048][64] bf16
    u16* kb      = (u16*)(ws + 25165824);
    u16* vb      = (u16*)(ws + 33554432);
    u16* valsb   = (u16*)(ws + 42467328);        // [4096][1024] bf16
    // partial buffers alias xb (dead after gemm_qkv)
    float* lp    = (float*)(ws);                 // [2][32][2048]
    float* cp    = (float*)(ws + 1048576);       // [2][32][2048]

    cast_f32_bf16<<<4096, 256, 0, stream>>>(x, xb, 1048576);
    transpose_cast<<<dim3(96, 32), dim3(32, 8), 0, stream>>>(wqkv, wqkvT, 1024, 3072);
    transpose_cast<<<dim3(32, 32), dim3(32, 8), 0, stream>>>(wo, woT, 1024, 1024);
    gemm_qkv<<<dim3(24, 32), 256, 0, stream>>>(xb, wqkvT, qb, kb, vb);
    attn_pass1<<<1024, 256, 0, stream>>>(qb, kb, lp);
    attn_pass2<<<1024, 256, 0, stream>>>(qb, kb, lp, cp);
    scale_v<<<2048, 256, 0, stream>>>(vb, cp, valsb);
    gemm_out<<<dim3(8, 64), 256, 0, stream>>>(valsb, woT, out);
}